// Round 2
// baseline (364.995 us; speedup 1.0000x reference)
//
#include <hip/hip_runtime.h>
#include <hip/hip_bf16.h>

#define DM 256
#define NH 8
#define HD 32
#define NLV 3
#define NPT 4
#define NLP 12
#define BB 16
#define LQ 300
#define NT 8400
#define MROWS (BB * NT)      // 134400
#define QROWS (BB * LQ)      // 4800

typedef __bf16 bf16x8 __attribute__((ext_vector_type(8)));
typedef float  f32x16 __attribute__((ext_vector_type(16)));

// ---------------------------------------------------------------------------
// Kernel 0: pre-tile weights to bf16 as plain transposes (W^T, row n contiguous
// in k).  Lane fragment for k-step g = 16 B at byte offset g*32 from a single
// per-lane base -> all 16 W loads use immediate offsets.
// blocks 0..255   -> Wf  = W_val^T  (256 x 256)
// blocks 256..543 -> Wf2 = [W_off | W_attn]^T (288 x 256)
// blocks 544..799 -> Wf3 = W_out^T  (256 x 256)
// ---------------------------------------------------------------------------
__global__ void k_wt(const float* __restrict__ W_val,
                     const float* __restrict__ W_off,
                     const float* __restrict__ W_attn,
                     const float* __restrict__ W_out,
                     __hip_bfloat16* __restrict__ Wf,
                     __hip_bfloat16* __restrict__ Wf2,
                     __hip_bfloat16* __restrict__ Wf3)
{
    const int n = blockIdx.x;
    const int k = threadIdx.x;
    if (n < 256) {
        Wf[(size_t)n * 256 + k] = __float2bfloat16(W_val[(size_t)k * 256 + n]);
    } else if (n < 544) {
        const int n2 = n - 256;   // 0..287
        float v = (n2 < 192) ? W_off[(size_t)k * 192 + n2]
                             : W_attn[(size_t)k * 96 + (n2 - 192)];
        Wf2[(size_t)n2 * 256 + k] = __float2bfloat16(v);
    } else {
        const int n3 = n - 544;   // 0..255
        Wf3[(size_t)n3 * 256 + k] = __float2bfloat16(W_out[(size_t)k * 256 + n3]);
    }
}

// ---------------------------------------------------------------------------
// Kernel 1 (merged): blocks [0, 4200)   -> value = input_flatten @ W_val + b_val
//                    blocks [4200,4350) -> [off|attn] = query @ [W_off|W_attn]+b
// Register-direct: no LDS, no barriers.  Lane l's A fragment for MFMA
// 32x32x16 is rows (l&31), k = g*16 + (l>>5)*8 + 0..7 -- a contiguous 32 B
// fp32 chunk of one A row, loaded straight from global and converted in
// registers.  W fragments direct from L2-resident W^T.  Depth-4 register
// ring keeps 8 loads in flight per wave; 16 fully independent k-steps.
// ---------------------------------------------------------------------------
__global__ __launch_bounds__(256) void k_mm1(
    const float* __restrict__ A,             // (134400, 256) fp32
    const __hip_bfloat16* __restrict__ Wf,   // W_val^T
    const float* __restrict__ bval,          // (256,)
    __hip_bfloat16* __restrict__ V,          // (16, 8, 8400, 32)
    const float* __restrict__ Q,             // (4800, 256) fp32
    const __hip_bfloat16* __restrict__ Wf2,  // [W_off|W_attn]^T
    const float* __restrict__ boff,          // (192,)
    const float* __restrict__ battn,         // (96,)
    float* __restrict__ off_out,             // (4800, 192)
    float* __restrict__ attn_out)            // (4800, 96)
{
    const int t    = threadIdx.x;
    const int wave = t >> 6;
    const int lane = t & 63;
    const int lm   = lane & 31;
    const int kh   = lane >> 5;

    if (blockIdx.x < MROWS / 32) {
        // ---------------- value projection ----------------
        const int m0 = blockIdx.x * 32;

        f32x16 acc[2];
#pragma unroll
        for (int j = 0; j < 2; j++)
#pragma unroll
            for (int e = 0; e < 16; e++) acc[j][e] = 0.f;

        const float* ap = A + (size_t)(m0 + lm) * 256 + kh * 8;
        const __hip_bfloat16* w0p = Wf + (size_t)(wave * 64 + lm) * 256 + kh * 8;
        const __hip_bfloat16* w1p = w0p + 32 * 256;

        float4 pa0[4], pa1[4];
        bf16x8 pw0[4], pw1[4];
#pragma unroll
        for (int g = 0; g < 4; ++g) {
            pa0[g] = *(const float4*)(ap + g * 16);
            pa1[g] = *(const float4*)(ap + g * 16 + 4);
            pw0[g] = *(const bf16x8*)(w0p + g * 16);
            pw1[g] = *(const bf16x8*)(w1p + g * 16);
        }
#pragma unroll
        for (int g = 0; g < 16; ++g) {
            const int s = g & 3;
            float4 a0 = pa0[s], a1 = pa1[s];
            bf16x8 b0 = pw0[s], b1 = pw1[s];
            if (g < 12) {
                pa0[s] = *(const float4*)(ap + (g + 4) * 16);
                pa1[s] = *(const float4*)(ap + (g + 4) * 16 + 4);
                pw0[s] = *(const bf16x8*)(w0p + (g + 4) * 16);
                pw1[s] = *(const bf16x8*)(w1p + (g + 4) * 16);
            }
            union { __hip_bfloat162 h2[4]; bf16x8 v; } ua;
            ua.h2[0] = __float22bfloat162_rn(make_float2(a0.x, a0.y));
            ua.h2[1] = __float22bfloat162_rn(make_float2(a0.z, a0.w));
            ua.h2[2] = __float22bfloat162_rn(make_float2(a1.x, a1.y));
            ua.h2[3] = __float22bfloat162_rn(make_float2(a1.z, a1.w));
            acc[0] = __builtin_amdgcn_mfma_f32_32x32x16_bf16(ua.v, b0, acc[0], 0, 0, 0);
            acc[1] = __builtin_amdgcn_mfma_f32_32x32x16_bf16(ua.v, b1, acc[1], 0, 0, 0);
        }

#pragma unroll
        for (int j = 0; j < 2; j++) {
            const int n  = wave * 64 + j * 32 + lm;
            const float bn = bval[n];
            const int h  = n >> 5;
            const int d  = n & 31;
#pragma unroll
            for (int r = 0; r < 16; r++) {
                int rl = (r & 3) + 8 * (r >> 2) + 4 * kh;
                int m  = m0 + rl;
                int b  = m / NT;
                int pos = m - b * NT;
                V[((size_t)(b * NH + h) * NT + pos) * HD + d] =
                    __float2bfloat16(acc[j][r] + bn);
            }
        }
    } else {
        // ---------------- offset/attention projection ----------------
        const int m0 = (blockIdx.x - MROWS / 32) * 32;
        if (wave >= 3) return;      // 150 blocks only; wave 3 idle

        f32x16 acc[3];
#pragma unroll
        for (int j = 0; j < 3; j++)
#pragma unroll
            for (int e = 0; e < 16; e++) acc[j][e] = 0.f;

        const float* ap = Q + (size_t)(m0 + lm) * 256 + kh * 8;
        const __hip_bfloat16* w0p = Wf2 + (size_t)(wave * 96 + lm) * 256 + kh * 8;
        const __hip_bfloat16* w1p = w0p + 32 * 256;
        const __hip_bfloat16* w2p = w0p + 64 * 256;

        float4 pa0[2], pa1[2];
        bf16x8 pw0[2], pw1[2], pw2[2];
#pragma unroll
        for (int g = 0; g < 2; ++g) {
            pa0[g] = *(const float4*)(ap + g * 16);
            pa1[g] = *(const float4*)(ap + g * 16 + 4);
            pw0[g] = *(const bf16x8*)(w0p + g * 16);
            pw1[g] = *(const bf16x8*)(w1p + g * 16);
            pw2[g] = *(const bf16x8*)(w2p + g * 16);
        }
#pragma unroll
        for (int g = 0; g < 16; ++g) {
            const int s = g & 1;
            float4 a0 = pa0[s], a1 = pa1[s];
            bf16x8 b0 = pw0[s], b1 = pw1[s], b2 = pw2[s];
            if (g < 14) {
                pa0[s] = *(const float4*)(ap + (g + 2) * 16);
                pa1[s] = *(const float4*)(ap + (g + 2) * 16 + 4);
                pw0[s] = *(const bf16x8*)(w0p + (g + 2) * 16);
                pw1[s] = *(const bf16x8*)(w1p + (g + 2) * 16);
                pw2[s] = *(const bf16x8*)(w2p + (g + 2) * 16);
            }
            union { __hip_bfloat162 h2[4]; bf16x8 v; } ua;
            ua.h2[0] = __float22bfloat162_rn(make_float2(a0.x, a0.y));
            ua.h2[1] = __float22bfloat162_rn(make_float2(a0.z, a0.w));
            ua.h2[2] = __float22bfloat162_rn(make_float2(a1.x, a1.y));
            ua.h2[3] = __float22bfloat162_rn(make_float2(a1.z, a1.w));
            acc[0] = __builtin_amdgcn_mfma_f32_32x32x16_bf16(ua.v, b0, acc[0], 0, 0, 0);
            acc[1] = __builtin_amdgcn_mfma_f32_32x32x16_bf16(ua.v, b1, acc[1], 0, 0, 0);
            acc[2] = __builtin_amdgcn_mfma_f32_32x32x16_bf16(ua.v, b2, acc[2], 0, 0, 0);
        }

#pragma unroll
        for (int j = 0; j < 3; j++) {
            const int n = wave * 96 + j * 32 + lm;
            const float bias_ = (n < 192) ? boff[n] : battn[n - 192];
#pragma unroll
            for (int r = 0; r < 16; r++) {
                int rl = (r & 3) + 8 * (r >> 2) + 4 * kh;
                int m  = m0 + rl;
                float v = acc[j][r] + bias_;
                if (n < 192) off_out[(size_t)m * 192 + n] = v;
                else         attn_out[(size_t)m * 96 + (n - 192)] = v;
            }
        }
    }
}

// ---------------------------------------------------------------------------
// Kernel 3: softmax + sampling.  2 queries per block (256 thr = 2 x 128).
// XCD-locality swizzle: bind batch image b to XCD b%8 so each XCD's L2 serves
// a 2-image V working set instead of the full 68.8 MB random mix.
// ---------------------------------------------------------------------------
__global__ __launch_bounds__(256) void k_sample(
    const float* __restrict__ off_raw,   // (4800, 192)  (h,l,p,2)
    const float* __restrict__ attn_raw,  // (4800, 96)   (h, l*4+p)
    const float* __restrict__ refp,      // (16, 300, 3, 2)
    const __hip_bfloat16* __restrict__ V,// (16, 8, 8400, 32)
    __hip_bfloat16* __restrict__ sampled)// (4800, 256) bf16
{
    const int t  = threadIdx.x;
    const int q2 = t >> 7;          // 0..1
    const int tq = t & 127;

    const int bid  = blockIdx.x;          // 0..2399
    const int xcd  = bid & 7;
    const int slot = bid >> 3;            // 0..299
    const int hi   = (slot >= 150) ? 1 : 0;
    const int b    = xcd + (hi << 3);
    const int bq   = b * LQ + (slot - hi * 150) * 2 + q2;

    __shared__ float aw[2][96];
    __shared__ float wc[2][96][4];
    __shared__ int   ic[2][96][4];

    if (tq < 8) {
        float v[12];
        float mx = -1e30f;
#pragma unroll
        for (int i = 0; i < 12; i++) {
            v[i] = attn_raw[(size_t)bq * 96 + tq * 12 + i];
            mx = fmaxf(mx, v[i]);
        }
        float s = 0.f;
#pragma unroll
        for (int i = 0; i < 12; i++) { v[i] = expf(v[i] - mx); s += v[i]; }
        float inv = 1.f / s;
#pragma unroll
        for (int i = 0; i < 12; i++) aw[q2][tq * 12 + i] = v[i] * inv;
    }
    __syncthreads();

    if (tq < 96) {
        const float dims[3]  = {80.f, 40.f, 20.f};
        const int startsl[3] = {0, 6400, 8000};
        const int idiml[3]   = {80, 40, 20};
        int h = tq / 12, lp = tq - h * 12, l = lp >> 2, p = lp & 3;
        float ox = off_raw[(size_t)bq * 192 + ((h * 3 + l) * 4 + p) * 2 + 0];
        float oy = off_raw[(size_t)bq * 192 + ((h * 3 + l) * 4 + p) * 2 + 1];
        float rx = refp[(size_t)bq * 6 + l * 2 + 0];
        float ry = refp[(size_t)bq * 6 + l * 2 + 1];
        float D  = dims[l];
        float lx = rx + ox / D;
        float ly = ry + oy / D;
        float ix = lx * D - 0.5f;
        float iy = ly * D - 0.5f;
        const int Dl = idiml[l];
        const int st = startsl[l];

        float fix = floorf(ix), fiy = floorf(iy);
        int ix0 = (int)fix, iy0 = (int)fiy;
        int ix1 = ix0 + 1, iy1 = iy0 + 1;
        float fx = ix - fix, fy = iy - fiy;

        float mx0 = (ix0 >= 0 && ix0 < Dl) ? 1.f : 0.f;
        float mx1 = (ix1 >= 0 && ix1 < Dl) ? 1.f : 0.f;
        float my0 = (iy0 >= 0 && iy0 < Dl) ? 1.f : 0.f;
        float my1 = (iy1 >= 0 && iy1 < Dl) ? 1.f : 0.f;

        int cx0 = min(max(ix0, 0), Dl - 1);
        int cx1 = min(max(ix1, 0), Dl - 1);
        int cy0 = min(max(iy0, 0), Dl - 1);
        int cy1 = min(max(iy1, 0), Dl - 1);

        float a = aw[q2][tq];
        wc[q2][tq][0] = (1.f - fx) * (1.f - fy) * mx0 * my0 * a;
        wc[q2][tq][1] = fx * (1.f - fy) * mx1 * my0 * a;
        wc[q2][tq][2] = (1.f - fx) * fy * mx0 * my1 * a;
        wc[q2][tq][3] = fx * fy * mx1 * my1 * a;
        ic[q2][tq][0] = (st + cy0 * Dl + cx0) * HD;
        ic[q2][tq][1] = (st + cy0 * Dl + cx1) * HD;
        ic[q2][tq][2] = (st + cy1 * Dl + cx0) * HD;
        ic[q2][tq][3] = (st + cy1 * Dl + cx1) * HD;
    }
    __syncthreads();

    const int h  = tq >> 4;
    const int dp = (tq & 15) * 2;
    const __hip_bfloat16* vb = V + (size_t)(b * NH + h) * NT * HD + dp;

    float acc0 = 0.f, acc1 = 0.f;
#pragma unroll
    for (int lp = 0; lp < 12; lp++) {
        const int s = h * 12 + lp;
        float4 w4 = *(const float4*)(&wc[q2][s][0]);
        int4   i4 = *(const int4*)(&ic[q2][s][0]);
        float2 v00 = __bfloat1622float2(*(const __hip_bfloat162*)(vb + i4.x));
        float2 v01 = __bfloat1622float2(*(const __hip_bfloat162*)(vb + i4.y));
        float2 v10 = __bfloat1622float2(*(const __hip_bfloat162*)(vb + i4.z));
        float2 v11 = __bfloat1622float2(*(const __hip_bfloat162*)(vb + i4.w));
        acc0 = fmaf(w4.x, v00.x, fmaf(w4.y, v01.x, fmaf(w4.z, v10.x, fmaf(w4.w, v11.x, acc0))));
        acc1 = fmaf(w4.x, v00.y, fmaf(w4.y, v01.y, fmaf(w4.z, v10.y, fmaf(w4.w, v11.y, acc1))));
    }
    *(__hip_bfloat162*)(sampled + (size_t)bq * 256 + h * 32 + dp) =
        __float22bfloat162_rn(make_float2(acc0, acc1));
}

// ---------------------------------------------------------------------------
// Kernel 4 (MFMA): out = sampled(bf16) @ W_out + b_out.  Register-direct:
// lane's A fragment is a single 16 B bf16 load; W from W_out^T; no LDS,
// no barriers, depth-4 ring.
// ---------------------------------------------------------------------------
__global__ __launch_bounds__(256) void k_outproj(
    const __hip_bfloat16* __restrict__ A,    // (4800, 256) bf16
    const __hip_bfloat16* __restrict__ Wf3,  // W_out^T
    const float* __restrict__ bias,          // (256,)
    float* __restrict__ out)                 // (4800, 256)
{
    const int t    = threadIdx.x;
    const int m0   = blockIdx.x * 32;
    const int wave = t >> 6;
    const int lane = t & 63;
    const int lm   = lane & 31;
    const int kh   = lane >> 5;

    f32x16 acc[2];
#pragma unroll
    for (int j = 0; j < 2; j++)
#pragma unroll
        for (int e = 0; e < 16; e++) acc[j][e] = 0.f;

    const __hip_bfloat16* ap  = A + (size_t)(m0 + lm) * 256 + kh * 8;
    const __hip_bfloat16* w0p = Wf3 + (size_t)(wave * 64 + lm) * 256 + kh * 8;
    const __hip_bfloat16* w1p = w0p + 32 * 256;

    bf16x8 pa[4], pw0[4], pw1[4];
#pragma unroll
    for (int g = 0; g < 4; ++g) {
        pa[g]  = *(const bf16x8*)(ap + g * 16);
        pw0[g] = *(const bf16x8*)(w0p + g * 16);
        pw1[g] = *(const bf16x8*)(w1p + g * 16);
    }
#pragma unroll
    for (int g = 0; g < 16; ++g) {
        const int s = g & 3;
        bf16x8 af = pa[s], b0 = pw0[s], b1 = pw1[s];
        if (g < 12) {
            pa[s]  = *(const bf16x8*)(ap + (g + 4) * 16);
            pw0[s] = *(const bf16x8*)(w0p + (g + 4) * 16);
            pw1[s] = *(const bf16x8*)(w1p + (g + 4) * 16);
        }
        acc[0] = __builtin_amdgcn_mfma_f32_32x32x16_bf16(af, b0, acc[0], 0, 0, 0);
        acc[1] = __builtin_amdgcn_mfma_f32_32x32x16_bf16(af, b1, acc[1], 0, 0, 0);
    }

#pragma unroll
    for (int j = 0; j < 2; j++) {
        const int n = wave * 64 + j * 32 + lm;
        const float bn = bias[n];
#pragma unroll
        for (int r = 0; r < 16; r++) {
            int rl = (r & 3) + 8 * (r >> 2) + 4 * kh;
            int m  = m0 + rl;
            out[(size_t)m * 256 + n] = acc[j][r] + bn;
        }
    }
}

// ---------------------------------------------------------------------------
extern "C" void kernel_launch(void* const* d_in, const int* in_sizes, int n_in,
                              void* d_out, int out_size, void* d_ws, size_t ws_size,
                              hipStream_t stream) {
    const float* query  = (const float*)d_in[0];
    const float* refp   = (const float*)d_in[1];
    const float* inputf = (const float*)d_in[2];
    const float* W_off  = (const float*)d_in[3];
    const float* b_off  = (const float*)d_in[4];
    const float* W_attn = (const float*)d_in[5];
    const float* b_attn = (const float*)d_in[6];
    const float* W_val  = (const float*)d_in[7];
    const float* b_val  = (const float*)d_in[8];
    const float* W_out  = (const float*)d_in[9];
    const float* b_out  = (const float*)d_in[10];
    float* out = (float*)d_out;

    char* ws = (char*)d_ws;
    __hip_bfloat16* value   = (__hip_bfloat16*)ws;                       // 68,812,800
    float* off_raw          = (float*)(ws + 68812800);                   //  3,686,400
    float* attn_raw         = (float*)(ws + 72499200);                   //  1,843,200
    __hip_bfloat16* sampled = (__hip_bfloat16*)(ws + 74342400);          //  2,457,600
    __hip_bfloat16* Wf      = (__hip_bfloat16*)(ws + 76800000);          //    131,072
    __hip_bfloat16* Wf2     = (__hip_bfloat16*)(ws + 76931072);          //    147,456
    __hip_bfloat16* Wf3     = (__hip_bfloat16*)(ws + 77078528);          //    131,072

    k_wt<<<800, 256, 0, stream>>>(W_val, W_off, W_attn, W_out, Wf, Wf2, Wf3);
    k_mm1<<<MROWS / 32 + QROWS / 32, 256, 0, stream>>>(
        inputf, Wf, b_val, value, query, Wf2, b_off, b_attn, off_raw, attn_raw);
    k_sample<<<QROWS / 2, 256, 0, stream>>>(off_raw, attn_raw, refp, value, sampled);
    k_outproj<<<QROWS / 32, 256, 0, stream>>>(sampled, Wf3, b_out, out);
}

// Round 3
// 268.067 us; speedup vs baseline: 1.3616x; 1.3616x over previous
//
#include <hip/hip_runtime.h>
#include <hip/hip_bf16.h>

#define DM 256
#define NH 8
#define HD 32
#define NLV 3
#define NPT 4
#define NLP 12
#define BB 16
#define LQ 300
#define NT 8400
#define MROWS (BB * NT)      // 134400
#define QROWS (BB * LQ)      // 4800
#define KP2 72               // padded LDS K-stride for A tiles (BK=64)

typedef __bf16 bf16x8 __attribute__((ext_vector_type(8)));
typedef float  f32x16 __attribute__((ext_vector_type(16)));

// ---------------------------------------------------------------------------
// Kernel 0: pre-tile weights to bf16, fragment-major (coalesced wave reads):
//   Wf [(k>>3)*2048 + n*8 + (k&7)]  -- lane fragment = 16 B contiguous,
//   consecutive n -> consecutive fragments -> 512 B/instr per wave.
// blocks 0..255   -> Wf  from W_val
// blocks 256..543 -> Wf2 from [W_off | W_attn]   (n-stride 2304 per k-tile)
// blocks 544..799 -> Wf3 from W_out
// ---------------------------------------------------------------------------
__global__ void k_wt(const float* __restrict__ W_val,
                     const float* __restrict__ W_off,
                     const float* __restrict__ W_attn,
                     const float* __restrict__ W_out,
                     __hip_bfloat16* __restrict__ Wf,
                     __hip_bfloat16* __restrict__ Wf2,
                     __hip_bfloat16* __restrict__ Wf3)
{
    const int n = blockIdx.x;
    const int k = threadIdx.x;
    if (n < 256) {
        Wf[(size_t)(k >> 3) * 2048 + n * 8 + (k & 7)] =
            __float2bfloat16(W_val[(size_t)k * 256 + n]);
    } else if (n < 544) {
        const int n2 = n - 256;   // 0..287
        float v = (n2 < 192) ? W_off[(size_t)k * 192 + n2]
                             : W_attn[(size_t)k * 96 + (n2 - 192)];
        Wf2[(size_t)(k >> 3) * 2304 + n2 * 8 + (k & 7)] = __float2bfloat16(v);
    } else {
        const int n3 = n - 544;   // 0..255
        Wf3[(size_t)(k >> 3) * 2048 + n3 * 8 + (k & 7)] =
            __float2bfloat16(W_out[(size_t)k * 256 + n3]);
    }
}

// ---------------------------------------------------------------------------
// Kernel 1 (merged): blocks [0, 4200)   -> value = input_flatten @ W_val + b_val
//                    blocks [4200,4350) -> [off|attn] = query @ [W_off|W_attn]+b
// (round-1 structure restored: LDS-staged A, ONE barrier/K-iter, W fragments
// coalesced direct from L2-resident fragment-major tiles.)
// ---------------------------------------------------------------------------
__global__ __launch_bounds__(256) void k_mm1(
    const float* __restrict__ A,             // (134400, 256) fp32
    const __hip_bfloat16* __restrict__ Wf,   // fragment-major W_val
    const float* __restrict__ bval,          // (256,)
    __hip_bfloat16* __restrict__ V,          // (16, 8, 8400, 32)
    const float* __restrict__ Q,             // (4800, 256) fp32
    const __hip_bfloat16* __restrict__ Wf2,  // fragment-major [W_off|W_attn]
    const float* __restrict__ boff,          // (192,)
    const float* __restrict__ battn,         // (96,)
    float* __restrict__ off_out,             // (4800, 192)
    float* __restrict__ attn_out)            // (4800, 96)
{
    __shared__ __hip_bfloat16 As[2][32 * KP2];   // 2 x 4.5 KB

    const int t    = threadIdx.x;
    const int wave = t >> 6;
    const int lane = t & 63;
    const int lm   = lane & 31;
    const int kh   = lane >> 5;
    const int lk   = kh * 8;
    const int ar   = t >> 3;          // A row 0..31
    const int ak   = (t & 7) * 8;     // A k-chunk 0..56

    if (blockIdx.x < MROWS / 32) {
        // ---------------- value projection ----------------
        const int m0 = blockIdx.x * 32;

        f32x16 acc[2];
#pragma unroll
        for (int j = 0; j < 2; j++)
#pragma unroll
            for (int e = 0; e < 16; e++) acc[j][e] = 0.f;

        const __hip_bfloat16* wf0 = Wf + (size_t)(wave * 64 + lm) * 8 + kh * 2048;

        {
            const float* ap = A + (size_t)(m0 + ar) * 256 + ak;
            float4 a0 = *(const float4*)ap;
            float4 a1 = *(const float4*)(ap + 4);
            union { __hip_bfloat162 h2[4]; bf16x8 v; } ua;
            ua.h2[0] = __float22bfloat162_rn(make_float2(a0.x, a0.y));
            ua.h2[1] = __float22bfloat162_rn(make_float2(a0.z, a0.w));
            ua.h2[2] = __float22bfloat162_rn(make_float2(a1.x, a1.y));
            ua.h2[3] = __float22bfloat162_rn(make_float2(a1.z, a1.w));
            *(bf16x8*)(&As[0][ar * KP2 + ak]) = ua.v;
        }
        __syncthreads();

#pragma unroll
        for (int it = 0; it < 4; ++it) {
            const int buf = it & 1;
            float4 na0, na1;
            if (it < 3) {
                const float* ap = A + (size_t)(m0 + ar) * 256 + (it + 1) * 64 + ak;
                na0 = *(const float4*)ap;
                na1 = *(const float4*)(ap + 4);
            }
#pragma unroll
            for (int ks = 0; ks < 4; ++ks) {
                const int g = it * 4 + ks;
                bf16x8 af = *(const bf16x8*)(&As[buf][lm * KP2 + ks * 16 + lk]);
                bf16x8 b0 = *(const bf16x8*)(wf0 + (size_t)g * 4096);
                bf16x8 b1 = *(const bf16x8*)(wf0 + (size_t)g * 4096 + 256);
                acc[0] = __builtin_amdgcn_mfma_f32_32x32x16_bf16(af, b0, acc[0], 0, 0, 0);
                acc[1] = __builtin_amdgcn_mfma_f32_32x32x16_bf16(af, b1, acc[1], 0, 0, 0);
            }
            if (it < 3) {
                union { __hip_bfloat162 h2[4]; bf16x8 v; } ua;
                ua.h2[0] = __float22bfloat162_rn(make_float2(na0.x, na0.y));
                ua.h2[1] = __float22bfloat162_rn(make_float2(na0.z, na0.w));
                ua.h2[2] = __float22bfloat162_rn(make_float2(na1.x, na1.y));
                ua.h2[3] = __float22bfloat162_rn(make_float2(na1.z, na1.w));
                *(bf16x8*)(&As[buf ^ 1][ar * KP2 + ak]) = ua.v;
                __syncthreads();
            }
        }

#pragma unroll
        for (int j = 0; j < 2; j++) {
            const int n  = wave * 64 + j * 32 + lm;
            const float bn = bval[n];
            const int h  = n >> 5;
            const int d  = n & 31;
#pragma unroll
            for (int r = 0; r < 16; r++) {
                int rl = (r & 3) + 8 * (r >> 2) + 4 * kh;
                int m  = m0 + rl;
                int b  = m / NT;
                int pos = m - b * NT;
                V[((size_t)(b * NH + h) * NT + pos) * HD + d] =
                    __float2bfloat16(acc[j][r] + bn);
            }
        }
    } else {
        // ---------------- offset/attention projection ----------------
        const int m0 = (blockIdx.x - MROWS / 32) * 32;

        f32x16 acc[3];
#pragma unroll
        for (int j = 0; j < 3; j++)
#pragma unroll
            for (int e = 0; e < 16; e++) acc[j][e] = 0.f;

        const __hip_bfloat16* wf0 = Wf2 + (size_t)(wave * 96 + lm) * 8 + kh * 2304;

        {
            const float* ap = Q + (size_t)(m0 + ar) * 256 + ak;
            float4 a0 = *(const float4*)ap;
            float4 a1 = *(const float4*)(ap + 4);
            union { __hip_bfloat162 h2[4]; bf16x8 v; } ua;
            ua.h2[0] = __float22bfloat162_rn(make_float2(a0.x, a0.y));
            ua.h2[1] = __float22bfloat162_rn(make_float2(a0.z, a0.w));
            ua.h2[2] = __float22bfloat162_rn(make_float2(a1.x, a1.y));
            ua.h2[3] = __float22bfloat162_rn(make_float2(a1.z, a1.w));
            *(bf16x8*)(&As[0][ar * KP2 + ak]) = ua.v;
        }
        __syncthreads();

#pragma unroll
        for (int it = 0; it < 4; ++it) {
            const int buf = it & 1;
            float4 na0, na1;
            if (it < 3) {
                const float* ap = Q + (size_t)(m0 + ar) * 256 + (it + 1) * 64 + ak;
                na0 = *(const float4*)ap;
                na1 = *(const float4*)(ap + 4);
            }
#pragma unroll
            for (int ks = 0; ks < 4; ++ks) {
                const int g = it * 4 + ks;
                bf16x8 af = *(const bf16x8*)(&As[buf][lm * KP2 + ks * 16 + lk]);
                if (wave < 3) {
#pragma unroll
                    for (int j = 0; j < 3; j++) {
                        bf16x8 bf = *(const bf16x8*)(wf0 + (size_t)g * 4608 + j * 256);
                        acc[j] = __builtin_amdgcn_mfma_f32_32x32x16_bf16(af, bf, acc[j], 0, 0, 0);
                    }
                }
            }
            if (it < 3) {
                union { __hip_bfloat162 h2[4]; bf16x8 v; } ua;
                ua.h2[0] = __float22bfloat162_rn(make_float2(na0.x, na0.y));
                ua.h2[1] = __float22bfloat162_rn(make_float2(na0.z, na0.w));
                ua.h2[2] = __float22bfloat162_rn(make_float2(na1.x, na1.y));
                ua.h2[3] = __float22bfloat162_rn(make_float2(na1.z, na1.w));
                *(bf16x8*)(&As[buf ^ 1][ar * KP2 + ak]) = ua.v;
                __syncthreads();
            }
        }

        if (wave < 3) {
#pragma unroll
            for (int j = 0; j < 3; j++) {
                const int n = wave * 96 + j * 32 + lm;
                const float bias_ = (n < 192) ? boff[n] : battn[n - 192];
#pragma unroll
                for (int r = 0; r < 16; r++) {
                    int rl = (r & 3) + 8 * (r >> 2) + 4 * kh;
                    int m  = m0 + rl;
                    float v = acc[j][r] + bias_;
                    if (n < 192) off_out[(size_t)m * 192 + n] = v;
                    else         attn_out[(size_t)m * 96 + (n - 192)] = v;
                }
            }
        }
    }
}

// ---------------------------------------------------------------------------
// Kernel 3: softmax + sampling, rewritten for gather efficiency.
// 256 threads = 4 queries x 64 lanes (8 heads x 8 threads, 4 dims/thread)
// -> gather loads are 8 B (uint2) instead of 4 B, all 256 lanes active.
// XCD-locality swizzle: image b -> XCD b%8 (1200 blocks = 8 x 2 x 75).
// ---------------------------------------------------------------------------
__global__ __launch_bounds__(256) void k_sample(
    const float* __restrict__ off_raw,   // (4800, 192)  (h,l,p,2)
    const float* __restrict__ attn_raw,  // (4800, 96)   (h, l*4+p)
    const float* __restrict__ refp,      // (16, 300, 3, 2)
    const __hip_bfloat16* __restrict__ V,// (16, 8, 8400, 32)
    __hip_bfloat16* __restrict__ sampled)// (4800, 256) bf16
{
    const int t = threadIdx.x;

    const int bid  = blockIdx.x;          // 0..1199
    const int xcd  = bid & 7;
    const int slot = bid >> 3;            // 0..149
    const int hi   = (slot >= 75) ? 1 : 0;
    const int b    = xcd + (hi << 3);
    const int q0   = (slot - hi * 75) * 4;
    const int bq0  = b * LQ + q0;

    __shared__ float aw[4][96];
    __shared__ float wc[4][96][4];
    __shared__ int   ic[4][96][4];

    // ---- phase A: softmax, 32 threads = 4 q x 8 heads, float4 loads ----
    if (t < 32) {
        const int q = t >> 3, h = t & 7;
        const float* arp = attn_raw + (size_t)(bq0 + q) * 96 + h * 12;
        float4 x0 = *(const float4*)arp;
        float4 x1 = *(const float4*)(arp + 4);
        float4 x2 = *(const float4*)(arp + 8);
        float v[12] = {x0.x, x0.y, x0.z, x0.w,
                       x1.x, x1.y, x1.z, x1.w,
                       x2.x, x2.y, x2.z, x2.w};
        float mx = -1e30f;
#pragma unroll
        for (int i = 0; i < 12; i++) mx = fmaxf(mx, v[i]);
        float s = 0.f;
#pragma unroll
        for (int i = 0; i < 12; i++) { v[i] = expf(v[i] - mx); s += v[i]; }
        float inv = 1.f / s;
#pragma unroll
        for (int i = 0; i < 12; i++) aw[q][h * 12 + i] = v[i] * inv;
    }
    __syncthreads();

    // ---- phase B: weights + indices, 384 items over 256 threads ----
#pragma unroll
    for (int i = t; i < 384; i += 256) {
        const int q  = i / 96;
        const int s  = i - q * 96;
        const int bq = bq0 + q;
        const float dims[3]  = {80.f, 40.f, 20.f};
        const int startsl[3] = {0, 6400, 8000};
        const int idiml[3]   = {80, 40, 20};
        int h = s / 12, lp = s - h * 12, l = lp >> 2, p = lp & 3;
        float2 o2 = *(const float2*)(off_raw + (size_t)bq * 192 + ((h * 3 + l) * 4 + p) * 2);
        float2 r2 = *(const float2*)(refp + (size_t)bq * 6 + l * 2);
        float D  = dims[l];
        float ix = (r2.x + o2.x / D) * D - 0.5f;
        float iy = (r2.y + o2.y / D) * D - 0.5f;
        const int Dl = idiml[l];
        const int st = startsl[l];

        float fix = floorf(ix), fiy = floorf(iy);
        int ix0 = (int)fix, iy0 = (int)fiy;
        int ix1 = ix0 + 1, iy1 = iy0 + 1;
        float fx = ix - fix, fy = iy - fiy;

        float mx0 = (ix0 >= 0 && ix0 < Dl) ? 1.f : 0.f;
        float mx1 = (ix1 >= 0 && ix1 < Dl) ? 1.f : 0.f;
        float my0 = (iy0 >= 0 && iy0 < Dl) ? 1.f : 0.f;
        float my1 = (iy1 >= 0 && iy1 < Dl) ? 1.f : 0.f;

        int cx0 = min(max(ix0, 0), Dl - 1);
        int cx1 = min(max(ix1, 0), Dl - 1);
        int cy0 = min(max(iy0, 0), Dl - 1);
        int cy1 = min(max(iy1, 0), Dl - 1);

        float a = aw[q][s];
        wc[q][s][0] = (1.f - fx) * (1.f - fy) * mx0 * my0 * a;
        wc[q][s][1] = fx * (1.f - fy) * mx1 * my0 * a;
        wc[q][s][2] = (1.f - fx) * fy * mx0 * my1 * a;
        wc[q][s][3] = fx * fy * mx1 * my1 * a;
        ic[q][s][0] = (st + cy0 * Dl + cx0) * HD;
        ic[q][s][1] = (st + cy0 * Dl + cx1) * HD;
        ic[q][s][2] = (st + cy1 * Dl + cx0) * HD;
        ic[q][s][3] = (st + cy1 * Dl + cx1) * HD;
    }
    __syncthreads();

    // ---- phase C: gather + weighted sum; 8-B loads, 4 dims/thread ----
    const int q  = t >> 6;
    const int u  = t & 63;
    const int h  = u >> 3;
    const int dt = (u & 7) * 4;       // dim base 0..28
    const int bq = bq0 + q;
    const __hip_bfloat16* vb = V + (size_t)(b * NH + h) * NT * HD + dt;

    float a0 = 0.f, a1 = 0.f, a2 = 0.f, a3 = 0.f;
#pragma unroll
    for (int lp = 0; lp < 12; lp++) {
        const int s = h * 12 + lp;
        float4 w4 = *(const float4*)(&wc[q][s][0]);
        int4   i4 = *(const int4*)(&ic[q][s][0]);
        union { uint2 u2; __hip_bfloat162 h2[2]; } c0, c1, c2, c3;
        c0.u2 = *(const uint2*)(vb + i4.x);
        c1.u2 = *(const uint2*)(vb + i4.y);
        c2.u2 = *(const uint2*)(vb + i4.z);
        c3.u2 = *(const uint2*)(vb + i4.w);
        float2 f0a = __bfloat1622float2(c0.h2[0]), f0b = __bfloat1622float2(c0.h2[1]);
        float2 f1a = __bfloat1622float2(c1.h2[0]), f1b = __bfloat1622float2(c1.h2[1]);
        float2 f2a = __bfloat1622float2(c2.h2[0]), f2b = __bfloat1622float2(c2.h2[1]);
        float2 f3a = __bfloat1622float2(c3.h2[0]), f3b = __bfloat1622float2(c3.h2[1]);
        a0 = fmaf(w4.x, f0a.x, fmaf(w4.y, f1a.x, fmaf(w4.z, f2a.x, fmaf(w4.w, f3a.x, a0))));
        a1 = fmaf(w4.x, f0a.y, fmaf(w4.y, f1a.y, fmaf(w4.z, f2a.y, fmaf(w4.w, f3a.y, a1))));
        a2 = fmaf(w4.x, f0b.x, fmaf(w4.y, f1b.x, fmaf(w4.z, f2b.x, fmaf(w4.w, f3b.x, a2))));
        a3 = fmaf(w4.x, f0b.y, fmaf(w4.y, f1b.y, fmaf(w4.z, f2b.y, fmaf(w4.w, f3b.y, a3))));
    }
    union { ushort4 s4; __hip_bfloat162 h2[2]; } ou;
    ou.h2[0] = __float22bfloat162_rn(make_float2(a0, a1));
    ou.h2[1] = __float22bfloat162_rn(make_float2(a2, a3));
    *(ushort4*)(sampled + (size_t)bq * 256 + h * 32 + dt) = ou.s4;
}

// ---------------------------------------------------------------------------
// Kernel 4 (MFMA): out = sampled(bf16) @ W_out + b_out.  (round-1 structure:
// LDS-staged A double-buffer, fragment-major W direct from L2.)
// ---------------------------------------------------------------------------
__global__ __launch_bounds__(256) void k_outproj(
    const __hip_bfloat16* __restrict__ A,    // (4800, 256) bf16
    const __hip_bfloat16* __restrict__ Wf3,  // fragment-major W_out
    const float* __restrict__ bias,          // (256,)
    float* __restrict__ out)                 // (4800, 256)
{
    __shared__ __hip_bfloat16 As[2][32 * KP2];

    const int t    = threadIdx.x;
    const int m0   = blockIdx.x * 32;
    const int wave = t >> 6;
    const int lane = t & 63;
    const int lm   = lane & 31;
    const int kh   = lane >> 5;
    const int lk   = kh * 8;
    const int ar   = t >> 3;
    const int ak   = (t & 7) * 8;

    f32x16 acc[2];
#pragma unroll
    for (int j = 0; j < 2; j++)
#pragma unroll
        for (int e = 0; e < 16; e++) acc[j][e] = 0.f;

    const __hip_bfloat16* wf0 = Wf3 + (size_t)(wave * 64 + lm) * 8 + kh * 2048;

    *(bf16x8*)(&As[0][ar * KP2 + ak]) =
        *(const bf16x8*)(A + (size_t)(m0 + ar) * 256 + ak);
    __syncthreads();

#pragma unroll
    for (int it = 0; it < 4; ++it) {
        const int buf = it & 1;
        bf16x8 na;
        if (it < 3)
            na = *(const bf16x8*)(A + (size_t)(m0 + ar) * 256 + (it + 1) * 64 + ak);
#pragma unroll
        for (int ks = 0; ks < 4; ++ks) {
            const int g = it * 4 + ks;
            bf16x8 af = *(const bf16x8*)(&As[buf][lm * KP2 + ks * 16 + lk]);
            bf16x8 b0 = *(const bf16x8*)(wf0 + (size_t)g * 4096);
            bf16x8 b1 = *(const bf16x8*)(wf0 + (size_t)g * 4096 + 256);
            acc[0] = __builtin_amdgcn_mfma_f32_32x32x16_bf16(af, b0, acc[0], 0, 0, 0);
            acc[1] = __builtin_amdgcn_mfma_f32_32x32x16_bf16(af, b1, acc[1], 0, 0, 0);
        }
        if (it < 3) {
            *(bf16x8*)(&As[buf ^ 1][ar * KP2 + ak]) = na;
            __syncthreads();
        }
    }

#pragma unroll
    for (int j = 0; j < 2; j++) {
        const int n = wave * 64 + j * 32 + lm;
        const float bn = bias[n];
#pragma unroll
        for (int r = 0; r < 16; r++) {
            int rl = (r & 3) + 8 * (r >> 2) + 4 * kh;
            int m  = m0 + rl;
            out[(size_t)m * 256 + n] = acc[j][r] + bn;
        }
    }
}

// ---------------------------------------------------------------------------
extern "C" void kernel_launch(void* const* d_in, const int* in_sizes, int n_in,
                              void* d_out, int out_size, void* d_ws, size_t ws_size,
                              hipStream_t stream) {
    const float* query  = (const float*)d_in[0];
    const float* refp   = (const float*)d_in[1];
    const float* inputf = (const float*)d_in[2];
    const float* W_off  = (const float*)d_in[3];
    const float* b_off  = (const float*)d_in[4];
    const float* W_attn = (const float*)d_in[5];
    const float* b_attn = (const float*)d_in[6];
    const float* W_val  = (const float*)d_in[7];
    const float* b_val  = (const float*)d_in[8];
    const float* W_out  = (const float*)d_in[9];
    const float* b_out  = (const float*)d_in[10];
    float* out = (float*)d_out;

    char* ws = (char*)d_ws;
    __hip_bfloat16* value   = (__hip_bfloat16*)ws;                       // 68,812,800
    float* off_raw          = (float*)(ws + 68812800);                   //  3,686,400
    float* attn_raw         = (float*)(ws + 72499200);                   //  1,843,200
    __hip_bfloat16* sampled = (__hip_bfloat16*)(ws + 74342400);          //  2,457,600
    __hip_bfloat16* Wf      = (__hip_bfloat16*)(ws + 76800000);          //    131,072
    __hip_bfloat16* Wf2     = (__hip_bfloat16*)(ws + 76931072);          //    147,456
    __hip_bfloat16* Wf3     = (__hip_bfloat16*)(ws + 77078528);          //    131,072

    k_wt<<<800, 256, 0, stream>>>(W_val, W_off, W_attn, W_out, Wf, Wf2, Wf3);
    k_mm1<<<MROWS / 32 + QROWS / 32, 256, 0, stream>>>(
        inputf, Wf, b_val, value, query, Wf2, b_off, b_attn, off_raw, attn_raw);
    k_sample<<<1200, 256, 0, stream>>>(off_raw, attn_raw, refp, value, sampled);
    k_outproj<<<QROWS / 32, 256, 0, stream>>>(sampled, Wf3, b_out, out);
}

// Round 4
// 261.889 us; speedup vs baseline: 1.3937x; 1.0236x over previous
//
#include <hip/hip_runtime.h>
#include <hip/hip_bf16.h>

#define DM 256
#define NH 8
#define HD 32
#define NLV 3
#define NPT 4
#define NLP 12
#define BB 16
#define LQ 300
#define NT 8400
#define MROWS (BB * NT)      // 134400
#define QROWS (BB * LQ)      // 4800
#define KP2 72               // padded LDS K-stride for A tiles (BK=64)
#define VB (MROWS / 64)      // 2100 valproj blocks

typedef __bf16 bf16x8 __attribute__((ext_vector_type(8)));
typedef float  f32x16 __attribute__((ext_vector_type(16)));

// ---------------------------------------------------------------------------
// Kernel 0: pre-tile weights to bf16, fragment-major (coalesced wave reads):
//   Wf [(k>>3)*2048 + n*8 + (k&7)]  -- lane fragment = 16 B contiguous,
//   consecutive n -> consecutive fragments -> 512 B/instr per wave.
// ---------------------------------------------------------------------------
__global__ void k_wt(const float* __restrict__ W_val,
                     const float* __restrict__ W_off,
                     const float* __restrict__ W_attn,
                     const float* __restrict__ W_out,
                     __hip_bfloat16* __restrict__ Wf,
                     __hip_bfloat16* __restrict__ Wf2,
                     __hip_bfloat16* __restrict__ Wf3)
{
    const int n = blockIdx.x;
    const int k = threadIdx.x;
    if (n < 256) {
        Wf[(size_t)(k >> 3) * 2048 + n * 8 + (k & 7)] =
            __float2bfloat16(W_val[(size_t)k * 256 + n]);
    } else if (n < 544) {
        const int n2 = n - 256;   // 0..287
        float v = (n2 < 192) ? W_off[(size_t)k * 192 + n2]
                             : W_attn[(size_t)k * 96 + (n2 - 192)];
        Wf2[(size_t)(k >> 3) * 2304 + n2 * 8 + (k & 7)] = __float2bfloat16(v);
    } else {
        const int n3 = n - 544;   // 0..255
        Wf3[(size_t)(k >> 3) * 2048 + n3 * 8 + (k & 7)] =
            __float2bfloat16(W_out[(size_t)k * 256 + n3]);
    }
}

// ---------------------------------------------------------------------------
// Kernel 1 (merged): blocks [0, 2100)    -> value proj, BM=64
//                    blocks [2100, 2250) -> [off|attn] = query @ Wf2 + b, BM=32
// Value proj: BM=64 doubles MFMA per barrier (16/wave/iter), halves block
// count (cold-start latency) and per-block W L2 re-reads.  Same 1-barrier
// double-buffered LDS A staging; W fragments direct from L2.
// ---------------------------------------------------------------------------
__global__ __launch_bounds__(256) void k_mm1(
    const float* __restrict__ A,             // (134400, 256) fp32
    const __hip_bfloat16* __restrict__ Wf,   // fragment-major W_val
    const float* __restrict__ bval,          // (256,)
    __hip_bfloat16* __restrict__ V,          // (16, 8, 8400, 32)
    const float* __restrict__ Q,             // (4800, 256) fp32
    const __hip_bfloat16* __restrict__ Wf2,  // fragment-major [W_off|W_attn]
    const float* __restrict__ boff,          // (192,)
    const float* __restrict__ battn,         // (96,)
    float* __restrict__ off_out,             // (4800, 192)
    float* __restrict__ attn_out)            // (4800, 96)
{
    __shared__ __hip_bfloat16 As[2][64 * KP2];   // 2 x 9 KB

    const int t    = threadIdx.x;
    const int wave = t >> 6;
    const int lane = t & 63;
    const int lm   = lane & 31;
    const int kh   = lane >> 5;
    const int lk   = kh * 8;

    if (blockIdx.x < VB) {
        // ---------------- value projection, BM=64 ----------------
        const int m0  = blockIdx.x * 64;
        const int ar2 = t >> 2;          // A row 0..63
        const int ak2 = (t & 3) * 16;    // A k-chunk 0,16,32,48

        f32x16 acc[2][2];
#pragma unroll
        for (int i = 0; i < 2; i++)
#pragma unroll
            for (int j = 0; j < 2; j++)
#pragma unroll
                for (int e = 0; e < 16; e++) acc[i][j][e] = 0.f;

        const __hip_bfloat16* wf0 = Wf + (size_t)(wave * 64 + lm) * 8 + kh * 2048;

        // prologue: stage A k-tile 0 into buf 0 (16 floats/thread)
        {
            const float* ap = A + (size_t)(m0 + ar2) * 256 + ak2;
            float4 a0 = *(const float4*)ap;
            float4 a1 = *(const float4*)(ap + 4);
            float4 a2 = *(const float4*)(ap + 8);
            float4 a3 = *(const float4*)(ap + 12);
            union { __hip_bfloat162 h2[4]; bf16x8 v; } u0, u1;
            u0.h2[0] = __float22bfloat162_rn(make_float2(a0.x, a0.y));
            u0.h2[1] = __float22bfloat162_rn(make_float2(a0.z, a0.w));
            u0.h2[2] = __float22bfloat162_rn(make_float2(a1.x, a1.y));
            u0.h2[3] = __float22bfloat162_rn(make_float2(a1.z, a1.w));
            u1.h2[0] = __float22bfloat162_rn(make_float2(a2.x, a2.y));
            u1.h2[1] = __float22bfloat162_rn(make_float2(a2.z, a2.w));
            u1.h2[2] = __float22bfloat162_rn(make_float2(a3.x, a3.y));
            u1.h2[3] = __float22bfloat162_rn(make_float2(a3.z, a3.w));
            *(bf16x8*)(&As[0][ar2 * KP2 + ak2])     = u0.v;
            *(bf16x8*)(&As[0][ar2 * KP2 + ak2 + 8]) = u1.v;
        }
        __syncthreads();

#pragma unroll
        for (int it = 0; it < 4; ++it) {
            const int buf = it & 1;
            float4 na0, na1, na2, na3;
            if (it < 3) {
                const float* ap = A + (size_t)(m0 + ar2) * 256 + (it + 1) * 64 + ak2;
                na0 = *(const float4*)ap;
                na1 = *(const float4*)(ap + 4);
                na2 = *(const float4*)(ap + 8);
                na3 = *(const float4*)(ap + 12);
            }
#pragma unroll
            for (int ks = 0; ks < 4; ++ks) {
                const int g = it * 4 + ks;
                bf16x8 af0 = *(const bf16x8*)(&As[buf][(lm)      * KP2 + ks * 16 + lk]);
                bf16x8 af1 = *(const bf16x8*)(&As[buf][(32 + lm) * KP2 + ks * 16 + lk]);
                bf16x8 b0  = *(const bf16x8*)(wf0 + (size_t)g * 4096);
                bf16x8 b1  = *(const bf16x8*)(wf0 + (size_t)g * 4096 + 256);
                acc[0][0] = __builtin_amdgcn_mfma_f32_32x32x16_bf16(af0, b0, acc[0][0], 0, 0, 0);
                acc[0][1] = __builtin_amdgcn_mfma_f32_32x32x16_bf16(af0, b1, acc[0][1], 0, 0, 0);
                acc[1][0] = __builtin_amdgcn_mfma_f32_32x32x16_bf16(af1, b0, acc[1][0], 0, 0, 0);
                acc[1][1] = __builtin_amdgcn_mfma_f32_32x32x16_bf16(af1, b1, acc[1][1], 0, 0, 0);
            }
            if (it < 3) {
                union { __hip_bfloat162 h2[4]; bf16x8 v; } u0, u1;
                u0.h2[0] = __float22bfloat162_rn(make_float2(na0.x, na0.y));
                u0.h2[1] = __float22bfloat162_rn(make_float2(na0.z, na0.w));
                u0.h2[2] = __float22bfloat162_rn(make_float2(na1.x, na1.y));
                u0.h2[3] = __float22bfloat162_rn(make_float2(na1.z, na1.w));
                u1.h2[0] = __float22bfloat162_rn(make_float2(na2.x, na2.y));
                u1.h2[1] = __float22bfloat162_rn(make_float2(na2.z, na2.w));
                u1.h2[2] = __float22bfloat162_rn(make_float2(na3.x, na3.y));
                u1.h2[3] = __float22bfloat162_rn(make_float2(na3.z, na3.w));
                *(bf16x8*)(&As[buf ^ 1][ar2 * KP2 + ak2])     = u0.v;
                *(bf16x8*)(&As[buf ^ 1][ar2 * KP2 + ak2 + 8]) = u1.v;
                __syncthreads();
            }
        }

        // epilogue: bias + bf16 + permuted store; boundary compare, no div
        const int bb  = m0 / NT;
        const int bnd = (bb + 1) * NT;
#pragma unroll
        for (int i = 0; i < 2; i++) {
#pragma unroll
            for (int j = 0; j < 2; j++) {
                const int n  = wave * 64 + j * 32 + lm;
                const float bn = bval[n];
                const int h  = n >> 5;
                const int d  = n & 31;
#pragma unroll
                for (int r = 0; r < 16; r++) {
                    int rl = (r & 3) + 8 * (r >> 2) + 4 * kh;
                    int m  = m0 + i * 32 + rl;
                    int b  = bb + ((m >= bnd) ? 1 : 0);
                    int pos = m - b * NT;
                    V[((size_t)(b * NH + h) * NT + pos) * HD + d] =
                        __float2bfloat16(acc[i][j][r] + bn);
                }
            }
        }
    } else {
        // ---------------- offset/attention projection, BM=32 ----------------
        const int m0 = (blockIdx.x - VB) * 32;
        const int ar = t >> 3;          // 0..31
        const int ak = (t & 7) * 8;     // 0..56

        f32x16 acc[3];
#pragma unroll
        for (int j = 0; j < 3; j++)
#pragma unroll
            for (int e = 0; e < 16; e++) acc[j][e] = 0.f;

        const __hip_bfloat16* wf0 = Wf2 + (size_t)(wave * 96 + lm) * 8 + kh * 2304;

        {
            const float* ap = Q + (size_t)(m0 + ar) * 256 + ak;
            float4 a0 = *(const float4*)ap;
            float4 a1 = *(const float4*)(ap + 4);
            union { __hip_bfloat162 h2[4]; bf16x8 v; } ua;
            ua.h2[0] = __float22bfloat162_rn(make_float2(a0.x, a0.y));
            ua.h2[1] = __float22bfloat162_rn(make_float2(a0.z, a0.w));
            ua.h2[2] = __float22bfloat162_rn(make_float2(a1.x, a1.y));
            ua.h2[3] = __float22bfloat162_rn(make_float2(a1.z, a1.w));
            *(bf16x8*)(&As[0][ar * KP2 + ak]) = ua.v;
        }
        __syncthreads();

#pragma unroll
        for (int it = 0; it < 4; ++it) {
            const int buf = it & 1;
            float4 na0, na1;
            if (it < 3) {
                const float* ap = Q + (size_t)(m0 + ar) * 256 + (it + 1) * 64 + ak;
                na0 = *(const float4*)ap;
                na1 = *(const float4*)(ap + 4);
            }
#pragma unroll
            for (int ks = 0; ks < 4; ++ks) {
                const int g = it * 4 + ks;
                bf16x8 af = *(const bf16x8*)(&As[buf][lm * KP2 + ks * 16 + lk]);
                if (wave < 3) {
#pragma unroll
                    for (int j = 0; j < 3; j++) {
                        bf16x8 bf = *(const bf16x8*)(wf0 + (size_t)g * 4608 + j * 256);
                        acc[j] = __builtin_amdgcn_mfma_f32_32x32x16_bf16(af, bf, acc[j], 0, 0, 0);
                    }
                }
            }
            if (it < 3) {
                union { __hip_bfloat162 h2[4]; bf16x8 v; } ua;
                ua.h2[0] = __float22bfloat162_rn(make_float2(na0.x, na0.y));
                ua.h2[1] = __float22bfloat162_rn(make_float2(na0.z, na0.w));
                ua.h2[2] = __float22bfloat162_rn(make_float2(na1.x, na1.y));
                ua.h2[3] = __float22bfloat162_rn(make_float2(na1.z, na1.w));
                *(bf16x8*)(&As[buf ^ 1][ar * KP2 + ak]) = ua.v;
                __syncthreads();
            }
        }

        if (wave < 3) {
#pragma unroll
            for (int j = 0; j < 3; j++) {
                const int n = wave * 96 + j * 32 + lm;
                const float bias_ = (n < 192) ? boff[n] : battn[n - 192];
#pragma unroll
                for (int r = 0; r < 16; r++) {
                    int rl = (r & 3) + 8 * (r >> 2) + 4 * kh;
                    int m  = m0 + rl;
                    float v = acc[j][r] + bias_;
                    if (n < 192) off_out[(size_t)m * 192 + n] = v;
                    else         attn_out[(size_t)m * 96 + (n - 192)] = v;
                }
            }
        }
    }
}

// ---------------------------------------------------------------------------
// Kernel 3: softmax + sampling.  256 threads = 4 q x 64 lanes, 8-B gathers.
// XCD-locality swizzle: image b -> XCD b%8 (1200 blocks = 8 x 2 x 75).
// ---------------------------------------------------------------------------
__global__ __launch_bounds__(256) void k_sample(
    const float* __restrict__ off_raw,   // (4800, 192)  (h,l,p,2)
    const float* __restrict__ attn_raw,  // (4800, 96)   (h, l*4+p)
    const float* __restrict__ refp,      // (16, 300, 3, 2)
    const __hip_bfloat16* __restrict__ V,// (16, 8, 8400, 32)
    __hip_bfloat16* __restrict__ sampled)// (4800, 256) bf16
{
    const int t = threadIdx.x;

    const int bid  = blockIdx.x;          // 0..1199
    const int xcd  = bid & 7;
    const int slot = bid >> 3;            // 0..149
    const int hi   = (slot >= 75) ? 1 : 0;
    const int b    = xcd + (hi << 3);
    const int q0   = (slot - hi * 75) * 4;
    const int bq0  = b * LQ + q0;

    __shared__ float aw[4][96];
    __shared__ float wc[4][96][4];
    __shared__ int   ic[4][96][4];

    if (t < 32) {
        const int q = t >> 3, h = t & 7;
        const float* arp = attn_raw + (size_t)(bq0 + q) * 96 + h * 12;
        float4 x0 = *(const float4*)arp;
        float4 x1 = *(const float4*)(arp + 4);
        float4 x2 = *(const float4*)(arp + 8);
        float v[12] = {x0.x, x0.y, x0.z, x0.w,
                       x1.x, x1.y, x1.z, x1.w,
                       x2.x, x2.y, x2.z, x2.w};
        float mx = -1e30f;
#pragma unroll
        for (int i = 0; i < 12; i++) mx = fmaxf(mx, v[i]);
        float s = 0.f;
#pragma unroll
        for (int i = 0; i < 12; i++) { v[i] = expf(v[i] - mx); s += v[i]; }
        float inv = 1.f / s;
#pragma unroll
        for (int i = 0; i < 12; i++) aw[q][h * 12 + i] = v[i] * inv;
    }
    __syncthreads();

#pragma unroll
    for (int i = t; i < 384; i += 256) {
        const int q  = i / 96;
        const int s  = i - q * 96;
        const int bq = bq0 + q;
        const float dims[3]  = {80.f, 40.f, 20.f};
        const int startsl[3] = {0, 6400, 8000};
        const int idiml[3]   = {80, 40, 20};
        int h = s / 12, lp = s - h * 12, l = lp >> 2, p = lp & 3;
        float2 o2 = *(const float2*)(off_raw + (size_t)bq * 192 + ((h * 3 + l) * 4 + p) * 2);
        float2 r2 = *(const float2*)(refp + (size_t)bq * 6 + l * 2);
        float D  = dims[l];
        float ix = (r2.x + o2.x / D) * D - 0.5f;
        float iy = (r2.y + o2.y / D) * D - 0.5f;
        const int Dl = idiml[l];
        const int st = startsl[l];

        float fix = floorf(ix), fiy = floorf(iy);
        int ix0 = (int)fix, iy0 = (int)fiy;
        int ix1 = ix0 + 1, iy1 = iy0 + 1;
        float fx = ix - fix, fy = iy - fiy;

        float mx0 = (ix0 >= 0 && ix0 < Dl) ? 1.f : 0.f;
        float mx1 = (ix1 >= 0 && ix1 < Dl) ? 1.f : 0.f;
        float my0 = (iy0 >= 0 && iy0 < Dl) ? 1.f : 0.f;
        float my1 = (iy1 >= 0 && iy1 < Dl) ? 1.f : 0.f;

        int cx0 = min(max(ix0, 0), Dl - 1);
        int cx1 = min(max(ix1, 0), Dl - 1);
        int cy0 = min(max(iy0, 0), Dl - 1);
        int cy1 = min(max(iy1, 0), Dl - 1);

        float a = aw[q][s];
        wc[q][s][0] = (1.f - fx) * (1.f - fy) * mx0 * my0 * a;
        wc[q][s][1] = fx * (1.f - fy) * mx1 * my0 * a;
        wc[q][s][2] = (1.f - fx) * fy * mx0 * my1 * a;
        wc[q][s][3] = fx * fy * mx1 * my1 * a;
        ic[q][s][0] = (st + cy0 * Dl + cx0) * HD;
        ic[q][s][1] = (st + cy0 * Dl + cx1) * HD;
        ic[q][s][2] = (st + cy1 * Dl + cx0) * HD;
        ic[q][s][3] = (st + cy1 * Dl + cx1) * HD;
    }
    __syncthreads();

    const int q  = t >> 6;
    const int u  = t & 63;
    const int h  = u >> 3;
    const int dt = (u & 7) * 4;       // dim base 0..28
    const int bq = bq0 + q;
    const __hip_bfloat16* vb = V + (size_t)(b * NH + h) * NT * HD + dt;

    float a0 = 0.f, a1 = 0.f, a2 = 0.f, a3 = 0.f;
#pragma unroll
    for (int lp = 0; lp < 12; lp++) {
        const int s = h * 12 + lp;
        float4 w4 = *(const float4*)(&wc[q][s][0]);
        int4   i4 = *(const int4*)(&ic[q][s][0]);
        union { uint2 u2; __hip_bfloat162 h2[2]; } c0, c1, c2, c3;
        c0.u2 = *(const uint2*)(vb + i4.x);
        c1.u2 = *(const uint2*)(vb + i4.y);
        c2.u2 = *(const uint2*)(vb + i4.z);
        c3.u2 = *(const uint2*)(vb + i4.w);
        float2 f0a = __bfloat1622float2(c0.h2[0]), f0b = __bfloat1622float2(c0.h2[1]);
        float2 f1a = __bfloat1622float2(c1.h2[0]), f1b = __bfloat1622float2(c1.h2[1]);
        float2 f2a = __bfloat1622float2(c2.h2[0]), f2b = __bfloat1622float2(c2.h2[1]);
        float2 f3a = __bfloat1622float2(c3.h2[0]), f3b = __bfloat1622float2(c3.h2[1]);
        a0 = fmaf(w4.x, f0a.x, fmaf(w4.y, f1a.x, fmaf(w4.z, f2a.x, fmaf(w4.w, f3a.x, a0))));
        a1 = fmaf(w4.x, f0a.y, fmaf(w4.y, f1a.y, fmaf(w4.z, f2a.y, fmaf(w4.w, f3a.y, a1))));
        a2 = fmaf(w4.x, f0b.x, fmaf(w4.y, f1b.x, fmaf(w4.z, f2b.x, fmaf(w4.w, f3b.x, a2))));
        a3 = fmaf(w4.x, f0b.y, fmaf(w4.y, f1b.y, fmaf(w4.z, f2b.y, fmaf(w4.w, f3b.y, a3))));
    }
    union { ushort4 s4; __hip_bfloat162 h2[2]; } ou;
    ou.h2[0] = __float22bfloat162_rn(make_float2(a0, a1));
    ou.h2[1] = __float22bfloat162_rn(make_float2(a2, a3));
    *(ushort4*)(sampled + (size_t)bq * 256 + h * 32 + dt) = ou.s4;
}

// ---------------------------------------------------------------------------
// Kernel 4 (MFMA): out = sampled(bf16) @ W_out + b_out.
// ---------------------------------------------------------------------------
__global__ __launch_bounds__(256) void k_outproj(
    const __hip_bfloat16* __restrict__ A,    // (4800, 256) bf16
    const __hip_bfloat16* __restrict__ Wf3,  // fragment-major W_out
    const float* __restrict__ bias,          // (256,)
    float* __restrict__ out)                 // (4800, 256)
{
    __shared__ __hip_bfloat16 As[2][32 * KP2];

    const int t    = threadIdx.x;
    const int m0   = blockIdx.x * 32;
    const int wave = t >> 6;
    const int lane = t & 63;
    const int lm   = lane & 31;
    const int kh   = lane >> 5;
    const int lk   = kh * 8;
    const int ar   = t >> 3;
    const int ak   = (t & 7) * 8;

    f32x16 acc[2];
#pragma unroll
    for (int j = 0; j < 2; j++)
#pragma unroll
        for (int e = 0; e < 16; e++) acc[j][e] = 0.f;

    const __hip_bfloat16* wf0 = Wf3 + (size_t)(wave * 64 + lm) * 8 + kh * 2048;

    *(bf16x8*)(&As[0][ar * KP2 + ak]) =
        *(const bf16x8*)(A + (size_t)(m0 + ar) * 256 + ak);
    __syncthreads();

#pragma unroll
    for (int it = 0; it < 4; ++it) {
        const int buf = it & 1;
        bf16x8 na;
        if (it < 3)
            na = *(const bf16x8*)(A + (size_t)(m0 + ar) * 256 + (it + 1) * 64 + ak);
#pragma unroll
        for (int ks = 0; ks < 4; ++ks) {
            const int g = it * 4 + ks;
            bf16x8 af = *(const bf16x8*)(&As[buf][lm * KP2 + ks * 16 + lk]);
            bf16x8 b0 = *(const bf16x8*)(wf0 + (size_t)g * 4096);
            bf16x8 b1 = *(const bf16x8*)(wf0 + (size_t)g * 4096 + 256);
            acc[0] = __builtin_amdgcn_mfma_f32_32x32x16_bf16(af, b0, acc[0], 0, 0, 0);
            acc[1] = __builtin_amdgcn_mfma_f32_32x32x16_bf16(af, b1, acc[1], 0, 0, 0);
        }
        if (it < 3) {
            *(bf16x8*)(&As[buf ^ 1][ar * KP2 + ak]) = na;
            __syncthreads();
        }
    }

#pragma unroll
    for (int j = 0; j < 2; j++) {
        const int n = wave * 64 + j * 32 + lm;
        const float bn = bias[n];
#pragma unroll
        for (int r = 0; r < 16; r++) {
            int rl = (r & 3) + 8 * (r >> 2) + 4 * kh;
            int m  = m0 + rl;
            out[(size_t)m * 256 + n] = acc[j][r] + bn;
        }
    }
}

// ---------------------------------------------------------------------------
extern "C" void kernel_launch(void* const* d_in, const int* in_sizes, int n_in,
                              void* d_out, int out_size, void* d_ws, size_t ws_size,
                              hipStream_t stream) {
    const float* query  = (const float*)d_in[0];
    const float* refp   = (const float*)d_in[1];
    const float* inputf = (const float*)d_in[2];
    const float* W_off  = (const float*)d_in[3];
    const float* b_off  = (const float*)d_in[4];
    const float* W_attn = (const float*)d_in[5];
    const float* b_attn = (const float*)d_in[6];
    const float* W_val  = (const float*)d_in[7];
    const float* b_val  = (const float*)d_in[8];
    const float* W_out  = (const float*)d_in[9];
    const float* b_out  = (const float*)d_in[10];
    float* out = (float*)d_out;

    char* ws = (char*)d_ws;
    __hip_bfloat16* value   = (__hip_bfloat16*)ws;                       // 68,812,800
    float* off_raw          = (float*)(ws + 68812800);                   //  3,686,400
    float* attn_raw         = (float*)(ws + 72499200);                   //  1,843,200
    __hip_bfloat16* sampled = (__hip_bfloat16*)(ws + 74342400);          //  2,457,600
    __hip_bfloat16* Wf      = (__hip_bfloat16*)(ws + 76800000);          //    131,072
    __hip_bfloat16* Wf2     = (__hip_bfloat16*)(ws + 76931072);          //    147,456
    __hip_bfloat16* Wf3     = (__hip_bfloat16*)(ws + 77078528);          //    131,072

    k_wt<<<800, 256, 0, stream>>>(W_val, W_off, W_attn, W_out, Wf, Wf2, Wf3);
    k_mm1<<<VB + QROWS / 32, 256, 0, stream>>>(
        inputf, Wf, b_val, value, query, Wf2, b_off, b_attn, off_raw, attn_raw);
    k_sample<<<1200, 256, 0, stream>>>(off_raw, attn_raw, refp, value, sampled);
    k_outproj<<<QROWS / 32, 256, 0, stream>>>(sampled, Wf3, b_out, out);
}